// Round 9
// baseline (155.199 us; speedup 1.0000x reference)
//
#include <hip/hip_runtime.h>
#include <math.h>

typedef _Float16 half8  __attribute__((ext_vector_type(8)));
typedef _Float16 half4v __attribute__((ext_vector_type(4)));
typedef __fp16   fp16x2 __attribute__((ext_vector_type(2)));
typedef float    f32x4  __attribute__((ext_vector_type(4)));
typedef float    f32x16 __attribute__((ext_vector_type(16)));

// swizzled-weight layout (halfs), 32x32x16 A-fragments:
//   A[m][k]: m = MT*32 + (lane&31), k = s*16 + (lane>>5)*8 + j
//   big layers: [s(16)][MT(8)][lane(64)][j(8)]
#define W1OFF 0        // [MT=8][64][8] = 4096   (one kstep, only k<2 real)
#define W2OFF 4096     // [16][8][64][8] = 65536
#define W3OFF 69632    // 65536
#define W4OFF 135168   // [16][64][8] = 8192  (one Mtile, m<3 real)
#define SWTOT 143360
#define OUT_PIX (16*128*128)

// ---------------- prep: swizzle weights (fp32 -> f16 frag-contiguous) + dx/dy tail ----
__global__ void inr_prep(const float* __restrict__ W1, const float* __restrict__ W2,
                         const float* __restrict__ W3, const float* __restrict__ W4,
                         const int* __restrict__ sidx, const float* __restrict__ sv,
                         _Float16* __restrict__ wsw, float* __restrict__ outtail)
{
    int tid = blockIdx.x * 256 + threadIdx.x;
    if (tid < 16) {
        int si = sidx[tid];
        outtail[tid]      = sv[2*si + 1];   // dx = shift[:,1]
        outtail[16 + tid] = sv[2*si + 0];   // dy = shift[:,0]
    }
    if (tid >= SWTOT) return;
    int kind, rel;
    if      (tid < W2OFF) { kind = 0; rel = tid; }
    else if (tid < W3OFF) { kind = 1; rel = tid - W2OFF; }
    else if (tid < W4OFF) { kind = 2; rel = tid - W3OFF; }
    else                  { kind = 3; rel = tid - W4OFF; }
    int j    = rel & 7;
    int lane = (rel >> 3) & 63;
    int blk  = rel >> 9;
    int m32  = lane & 31;
    int hsel = lane >> 5;
    float val;
    if (kind == 3) {                       // blk = s; W4: A[m][k] = W4[k][m], m<3 else 0
        int k = blk*16 + hsel*8 + j;
        val = (m32 < 3) ? W4[k*3 + m32] : 0.0f;
    } else if (kind == 0) {                // blk = MT (s=0); K padded 2->16
        int m = blk*32 + m32;
        int k = hsel*8 + j;
        val = (k < 2) ? W1[k*256 + m] : 0.0f;
    } else {                               // blk = s*8 + MT
        int MT = blk & 7, s = blk >> 3;
        int m = MT*32 + m32;
        int k = s*16 + hsel*8 + j;
        val = (kind == 1) ? W2[k*256 + m] : W3[k*256 + m];
    }
    wsw[tid] = (_Float16)val;
}

// ---------------- fused MLP ----------------
// LDS activation layout: granule-major.  Element (pixel, hid) lives at
//   hbuf[(hid>>3)*1024 + pixel*8 + (hid&7)]     (granule = 8 halfs = 16 B, 128 px)
// 256 threads = 4 waves; wave w owns M-rows 64w..64w+63 (2 Mtiles of 32), all 128 px
// (4 Ntiles of 32).  MFMA 32x32x16: B[k][n]: n = lane&31, k = (lane>>5)*8 + j.
template<int NKS>
__device__ __forceinline__ void do_layer(const half8* __restrict__ Asw,
                                         const float* __restrict__ bias,
                                         _Float16* hbuf, int w, int m32, int hsel, int lane)
{
    f32x16 acc[2][4];
#pragma unroll
    for (int mt = 0; mt < 2; ++mt)
#pragma unroll
        for (int nt = 0; nt < 4; ++nt)
#pragma unroll
            for (int i = 0; i < 16; ++i)
                acc[mt][nt][i] = 0.0f;

#pragma unroll
    for (int s = 0; s < NKS; ++s) {
        half8 aw[2];                                   // weights: global dwordx4, L2-hot
#pragma unroll
        for (int mt = 0; mt < 2; ++mt)
            aw[mt] = Asw[(s*8 + 2*w + mt)*64 + lane];
        half8 bf[4];                                   // activations: ds_read_b128
        int g = s*2 + hsel;
#pragma unroll
        for (int nt = 0; nt < 4; ++nt)
            bf[nt] = *(const half8*)&hbuf[g*1024 + (32*nt + m32)*8];
#pragma unroll
        for (int nt = 0; nt < 4; ++nt)
#pragma unroll
            for (int mt = 0; mt < 2; ++mt)
                acc[mt][nt] = __builtin_amdgcn_mfma_f32_32x32x16_f16(aw[mt], bf[nt], acc[mt][nt], 0, 0, 0);
    }
    __syncthreads();                                   // all reads of hbuf done
    // epilogue: bias + relu (f32), packed cvt; 4 consecutive hids -> one b64 write
#pragma unroll
    for (int mt = 0; mt < 2; ++mt) {
#pragma unroll
        for (int g4 = 0; g4 < 4; ++g4) {
            int hid0 = 32*(2*w + mt) + 8*g4 + 4*hsel;  // rows for regs 4*g4..4*g4+3
            f32x4 bv = *(const f32x4*)&bias[hid0];
            int gg = 4*(2*w + mt) + g4;
            int o  = 4*hsel;
#pragma unroll
            for (int nt = 0; nt < 4; ++nt) {
                int pixel = 32*nt + m32;
                fp16x2 lo = __builtin_amdgcn_cvt_pkrtz(fmaxf(acc[mt][nt][4*g4+0] + bv[0], 0.f),
                                                       fmaxf(acc[mt][nt][4*g4+1] + bv[1], 0.f));
                fp16x2 hi = __builtin_amdgcn_cvt_pkrtz(fmaxf(acc[mt][nt][4*g4+2] + bv[2], 0.f),
                                                       fmaxf(acc[mt][nt][4*g4+3] + bv[3], 0.f));
                half4v hv;
                hv[0] = (_Float16)lo[0]; hv[1] = (_Float16)lo[1];
                hv[2] = (_Float16)hi[0]; hv[3] = (_Float16)hi[1];
                *(half4v*)&hbuf[gg*1024 + pixel*8 + o] = hv;
            }
        }
    }
    __syncthreads();
}

__launch_bounds__(256, 2)
__global__ void inr_fused(const float* __restrict__ x, const int* __restrict__ sidx_p,
                          const float* __restrict__ sv, const float* __restrict__ ra,
                          const float* __restrict__ cs, const float* __restrict__ csh,
                          const float* __restrict__ b1, const float* __restrict__ b2,
                          const float* __restrict__ b3, const float* __restrict__ b4,
                          const _Float16* __restrict__ wsw, float* __restrict__ out)
{
    __shared__ __align__(16) _Float16 hbuf[32768];     // 128 px x 256 hid, 64 KB
    int t = threadIdx.x;
    int lane = t & 63, w = t >> 6;
    int m32 = lane & 31, hsel = lane >> 5;
    int pixbase = blockIdx.x * 128;
    int b = pixbase >> 14;                             // 16384 px per image
    int sidx = sidx_p[b];
    float dy = sv[2*sidx], dx = sv[2*sidx + 1];
    float ang = ra[sidx];
    float sn, cn;
    sincosf(ang, &sn, &cn);

    // stage coords: layer-1 K=16 -> granules 0,1; uv at hid 0,1; rest zero
    if (t < 128) {
        int p = t;
        float x0 = x[(pixbase + p)*2 + 0];
        float x1 = x[(pixbase + p)*2 + 1];
        float u = cn*x0 - sn*x1 + dx;
        float v = sn*x0 + cn*x1 + dy;
        half8 z;
#pragma unroll
        for (int i = 0; i < 8; ++i) z[i] = (_Float16)0.0f;
        *(half8*)&hbuf[1*1024 + p*8] = z;
        z[0] = (_Float16)u; z[1] = (_Float16)v;
        *(half8*)&hbuf[0*1024 + p*8] = z;
    }
    __syncthreads();

    const half8* wsw8 = (const half8*)wsw;
    do_layer<1> (wsw8 + (W1OFF >> 3), b1, hbuf, w, m32, hsel, lane);   // layer 1 (K padded)
    do_layer<16>(wsw8 + (W2OFF >> 3), b2, hbuf, w, m32, hsel, lane);   // layer 2
    do_layer<16>(wsw8 + (W3OFF >> 3), b3, hbuf, w, m32, hsel, lane);   // layer 3

    // layer 4: one 32x32 tile chain; wave w -> pixels 32w..32w+31
    const half8* w4p = wsw8 + (W4OFF >> 3);
    f32x16 a4;
#pragma unroll
    for (int i = 0; i < 16; ++i) a4[i] = 0.0f;
#pragma unroll
    for (int s = 0; s < 16; ++s) {
        half8 aw = w4p[s*64 + lane];
        half8 bf = *(const half8*)&hbuf[(s*2 + hsel)*1024 + (32*w + m32)*8];
        a4 = __builtin_amdgcn_mfma_f32_32x32x16_f16(aw, bf, a4, 0, 0, 0);
    }
    if (lane < 32) {                                   // hsel==0: regs 0,1,2 = rows 0,1,2
        bool doc = (sidx != 0);
        float s0 = cs[sidx*3+0], s1 = cs[sidx*3+1], s2 = cs[sidx*3+2];
        float t0 = csh[sidx*3+0], t1 = csh[sidx*3+1], t2 = csh[sidx*3+2];
        float v0 = a4[0] + b4[0];
        float v1 = a4[1] + b4[1];
        float v2 = a4[2] + b4[2];
        if (doc) { v0 = v0*s0 + t0; v1 = v1*s1 + t1; v2 = v2*s2 + t2; }
        int gp = pixbase + 32*w + lane;
        out[gp*3 + 0] = v0;
        out[gp*3 + 1] = v1;
        out[gp*3 + 2] = v2;
    }
}

extern "C" void kernel_launch(void* const* d_in, const int* in_sizes, int n_in,
                              void* d_out, int out_size, void* d_ws, size_t ws_size,
                              hipStream_t stream)
{
    const float* x    = (const float*)d_in[0];
    const int*   sidx = (const int*)  d_in[1];
    const float* sv   = (const float*)d_in[2];
    const float* ra   = (const float*)d_in[3];
    const float* cs   = (const float*)d_in[4];
    const float* csh  = (const float*)d_in[5];
    const float* W1   = (const float*)d_in[6];
    const float* b1   = (const float*)d_in[7];
    const float* W2   = (const float*)d_in[8];
    const float* b2   = (const float*)d_in[9];
    const float* W3   = (const float*)d_in[10];
    const float* b3   = (const float*)d_in[11];
    const float* W4   = (const float*)d_in[12];
    const float* b4   = (const float*)d_in[13];
    float* out = (float*)d_out;
    _Float16* wsw = (_Float16*)d_ws;

    inr_prep<<<SWTOT/256, 256, 0, stream>>>(W1, W2, W3, W4, sidx, sv, wsw, out + OUT_PIX*3);
    inr_fused<<<OUT_PIX/128, 256, 0, stream>>>(x, sidx, sv, ra, cs, csh,
                                               b1, b2, b3, b4, wsw, out);
}